// Round 3
// baseline (811.857 us; speedup 1.0000x reference)
//
#include <hip/hip_runtime.h>
#include <hip/hip_bf16.h>

// GraphNetwork GAT: B=4, N=2048, I=32, H=64, O=32, E=2, HD=2, D1=256
// Inputs fp32, output fp32 (reference dtypes); comparator rounds to bf16 domain.

constexpr int B_  = 4;
constexpr int N_  = 2048;
constexpr int I_  = 32;
constexpr int H_  = 64;
constexpr int O_  = 32;
constexpr int EH_ = 4;        // E*HD combos, c = e*2 + h
constexpr int D1_ = 256;      // H*HD*E
constexpr int BN_ = B_ * N_;  // 8192
constexpr int NC_ = 16;       // i-chunks for softmax stats
constexpr int CH_ = N_ / NC_; // 128
constexpr int TI_ = 32;       // msg rows per block in MAC sweep
constexpr int TK_ = 32;       // k-tile in MAC sweep

__device__ __forceinline__ float lrelu(float x) { return fmaxf(x, 0.2f * x); }

// ---------------------------------------------------------------- embedding
// state0[b,n,h] = sum_i nodes[b,n,i]*W_emb[i,h] + b_emb[h]
__global__ void embed_kernel(const float* __restrict__ nodes, const float* __restrict__ W_emb,
                             const float* __restrict__ b_emb, float* __restrict__ state0) {
    int t = threadIdx.x;                 // 256
    int r = t >> 6, h = t & 63;
    int bn = blockIdx.x * 4 + r;
    __shared__ float sn[4][I_];
    if (t < 4 * I_) {
        int rr = t / I_, ii = t % I_;
        sn[rr][ii] = nodes[(size_t)(blockIdx.x * 4 + rr) * I_ + ii];
    }
    __syncthreads();
    float acc = b_emb[h];
    #pragma unroll
    for (int i = 0; i < I_; ++i) acc += sn[r][i] * W_emb[i * H_ + h];
    state0[(size_t)bn * H_ + h] = acc;
}

// ---------------------------------------------------- Wh + attention logits
// Wh[c,bn,k] = sum_d state[bn,d]*Wf[c,d,k];  a1/a2 = Wh . w1/w2 + b1/b2
template <int DIN>
__global__ void wh_a_kernel(const float* __restrict__ state, const float* __restrict__ Wf,
                            const float* __restrict__ w1, const float* __restrict__ b1,
                            const float* __restrict__ w2, const float* __restrict__ b2,
                            float* __restrict__ Wh, float* __restrict__ a1,
                            float* __restrict__ a2) {
    int blk = blockIdx.x;          // EH_*BN_
    int c = blk / BN_, bn = blk % BN_;
    int k = threadIdx.x;           // 64 = 1 wave
    __shared__ float ss[DIN];
    for (int d = k; d < DIN; d += 64) ss[d] = state[(size_t)bn * DIN + d];
    __syncthreads();
    const float* wf = Wf + (size_t)c * DIN * H_;
    float acc = 0.f;
    #pragma unroll 8
    for (int d = 0; d < DIN; ++d) acc += ss[d] * wf[d * H_ + k];
    Wh[((size_t)c * BN_ + bn) * H_ + k] = acc;
    float t1 = acc * w1[c * H_ + k];
    float t2 = acc * w2[c * H_ + k];
    #pragma unroll
    for (int m = 32; m; m >>= 1) { t1 += __shfl_xor(t1, m, 64); t2 += __shfl_xor(t2, m, 64); }
    if (k == 0) {
        a1[(size_t)c * BN_ + bn] = t1 + b1[c];
        a2[(size_t)c * BN_ + bn] = t2 + b2[c];
    }
}

// -------------------------------------------------- column softmax stats
// online (m,s) over i-chunk for each (c,b,j); l = lrelu(a1[i]+a2[j]) + edges[b,i,j,e]
__global__ void stats_kernel(const float* __restrict__ edges, const float* __restrict__ a1,
                             const float* __restrict__ a2, float* __restrict__ pm,
                             float* __restrict__ ps) {
    int blk = blockIdx.x;                       // B*NC*(N/256) = 512
    int jt = blk & 7;                           // N/256 = 8
    int ic = (blk >> 3) & (NC_ - 1);
    int b  = blk >> 7;
    int t = threadIdx.x;
    int j = jt * 256 + t;
    __shared__ float sa1[EH_][CH_];
    for (int q = t; q < EH_ * CH_; q += 256) {
        int cc = q / CH_, ii = q % CH_;
        sa1[cc][ii] = a1[(size_t)cc * BN_ + b * N_ + ic * CH_ + ii];
    }
    __syncthreads();
    float a2v[EH_], m[EH_], s[EH_];
    #pragma unroll
    for (int cc = 0; cc < EH_; ++cc) {
        a2v[cc] = a2[(size_t)cc * BN_ + b * N_ + j];
        m[cc] = -1e30f; s[cc] = 0.f;
    }
    const float2* ep = (const float2*)edges + ((size_t)(b * N_ + ic * CH_)) * N_ + j;
    for (int ii = 0; ii < CH_; ++ii) {
        float2 u = ep[(size_t)ii * N_];
        float e0 = u.x, e1 = u.y;
        #pragma unroll
        for (int cc = 0; cc < EH_; ++cc) {
            float x = sa1[cc][ii] + a2v[cc];
            float l = lrelu(x) + ((cc < 2) ? e0 : e1);
            float mn = fmaxf(m[cc], l);
            s[cc] = s[cc] * __expf(m[cc] - mn) + __expf(l - mn);
            m[cc] = mn;
        }
    }
    #pragma unroll
    for (int cc = 0; cc < EH_; ++cc) {
        size_t q = ((size_t)ic * EH_ + cc) * BN_ + b * N_ + j;
        pm[q] = m[cc]; ps[q] = s[cc];
    }
}

__global__ void combine_kernel(const float* __restrict__ pm, const float* __restrict__ ps,
                               float* __restrict__ mcol, float* __restrict__ invS) {
    int q = blockIdx.x * 256 + threadIdx.x;     // EH_*BN_ = 32768
    float M = -1e30f;
    #pragma unroll
    for (int ic = 0; ic < NC_; ++ic) M = fmaxf(M, pm[(size_t)ic * EH_ * BN_ + q]);
    float S = 0.f;
    #pragma unroll
    for (int ic = 0; ic < NC_; ++ic)
        S += ps[(size_t)ic * EH_ * BN_ + q] * __expf(pm[(size_t)ic * EH_ * BN_ + q] - M);
    mcol[q] = M;
    invS[q] = 1.f / S;
}

// ------------------------------------------------------------- MAC sweep
// msg[c,b,i,d] = sum_k att[c,b,i,k] * Wh[c,b,k,d], att recomputed on the fly.
// LAST=0: state1[b,i,c*64+d] = msg + bias0[h,d]
// LAST=1: state2[b,i,d] = mean_c elu(msg + bias1[h,d])
template <int LAST>
__global__ __launch_bounds__(512) void mac_kernel(
        const float* __restrict__ edges, const float* __restrict__ a1,
        const float* __restrict__ a2, const float* __restrict__ mcol,
        const float* __restrict__ invS, const float* __restrict__ Wh,
        const float* __restrict__ bias, float* __restrict__ out) {
    int t = threadIdx.x;                    // 512
    int blk = blockIdx.x;                   // B*(N/TI) = 256
    int b = blk >> 6;
    int i0 = (blk & 63) * TI_;
    int c = t >> 7, g = t & 127, dg = g >> 3, ig = g & 7;
    int d0 = dg * 4;

    __shared__ __align__(16) float satt[EH_][TK_][TI_ + 4];   // pad 4: 16B-aligned rows
    __shared__ float sa1s[EH_][TI_];
    __shared__ float sa2[EH_][TK_], sm[EH_][TK_], sis[EH_][TK_];
    __shared__ float sout[TI_][H_];

    for (int q = t; q < EH_ * TI_; q += 512)
        sa1s[q / TI_][q % TI_] = a1[(size_t)(q / TI_) * BN_ + b * N_ + i0 + (q % TI_)];

    float acc[4][4] = {};   // acc[di][ii]

    for (int k0 = 0; k0 < N_; k0 += TK_) {
        __syncthreads();    // protect satt/sa2 of previous tile (and sa1s at k0=0)
        for (int q = t; q < EH_ * TK_; q += 512) {
            int cc = q / TK_, kk = q % TK_;
            size_t idx = (size_t)cc * BN_ + b * N_ + k0 + kk;
            sa2[cc][kk] = a2[idx]; sm[cc][kk] = mcol[idx]; sis[cc][kk] = invS[idx];
        }
        __syncthreads();
        #pragma unroll
        for (int q = 0; q < 2; ++q) {       // TI*TK = 1024 positions / 512 threads
            int p = t + q * 512;
            int il = p >> 5, kl = p & 31;
            float2 u = *((const float2*)edges +
                         ((size_t)(b * N_ + i0 + il)) * N_ + k0 + kl);
            float e0 = u.x, e1 = u.y;
            #pragma unroll
            for (int cc = 0; cc < EH_; ++cc) {
                float x = sa1s[cc][il] + sa2[cc][kl];
                float l = lrelu(x) + ((cc < 2) ? e0 : e1);
                satt[cc][kl][il] = __expf(l - sm[cc][kl]) * sis[cc][kl];
            }
        }
        __syncthreads();
        const float* whp = Wh + ((size_t)c * BN_ + b * N_ + k0) * H_ + d0;
        const float* ap0 = &satt[c][0][ig * 4];
        #pragma unroll 8
        for (int kk = 0; kk < TK_; ++kk) {
            float4 w  = *(const float4*)(whp + (size_t)kk * H_);
            float4 av = *(const float4*)(ap0 + kk * (TI_ + 4));
            float wv[4] = {w.x, w.y, w.z, w.w};
            float avv[4] = {av.x, av.y, av.z, av.w};
            #pragma unroll
            for (int di = 0; di < 4; ++di)
                #pragma unroll
                for (int ii = 0; ii < 4; ++ii) acc[di][ii] += wv[di] * avv[ii];
        }
    }

    float bv[4];
    #pragma unroll
    for (int di = 0; di < 4; ++di) bv[di] = bias[(c & 1) * H_ + d0 + di];

    if (LAST) {
        #pragma unroll
        for (int cc = 0; cc < EH_; ++cc) {
            if (c == cc) {
                #pragma unroll
                for (int ii = 0; ii < 4; ++ii)
                    #pragma unroll
                    for (int di = 0; di < 4; ++di) {
                        float x = acc[di][ii] + bv[di];
                        float e = x > 0.f ? x : (__expf(x) - 1.f);
                        if (cc == 0) sout[ig * 4 + ii][d0 + di] = e;
                        else         sout[ig * 4 + ii][d0 + di] += e;
                    }
            }
            __syncthreads();
        }
        for (int q = t; q < TI_ * H_; q += 512) {
            int ii = q >> 6, dd = q & 63;
            out[((size_t)b * N_ + i0 + ii) * H_ + dd] = sout[ii][dd] * 0.25f;
        }
    } else {
        #pragma unroll
        for (int ii = 0; ii < 4; ++ii) {
            float4 v = make_float4(acc[0][ii] + bv[0], acc[1][ii] + bv[1],
                                   acc[2][ii] + bv[2], acc[3][ii] + bv[3]);
            *(float4*)(out + ((size_t)b * N_ + i0 + ig * 4 + ii) * D1_ + c * H_ + d0) = v;
        }
    }
}

// ------------------------------------------------------------- final output
// out[b,o] = b_out[o] + (1/N) * sum_d (sum_n state2[b,n,d]) * W_out[d,o]
__global__ void out_kernel(const float* __restrict__ state2, const float* __restrict__ W_out,
                           const float* __restrict__ b_out, float* __restrict__ out) {
    int b = blockIdx.x, t = threadIdx.x;    // 256
    int d = t & 63, nc = t >> 6;
    float psum = 0.f;
    const float* sp = state2 + ((size_t)b * N_ + nc * (N_ / 4)) * H_ + d;
    for (int n = 0; n < N_ / 4; ++n) psum += sp[(size_t)n * H_];
    __shared__ float red[4][H_];
    red[nc][d] = psum;
    __syncthreads();
    if (t < H_) red[0][d] = red[0][d] + red[1][d] + red[2][d] + red[3][d];
    __syncthreads();
    if (t < O_) {
        float acc = b_out[t];
        #pragma unroll 8
        for (int dd = 0; dd < H_; ++dd)
            acc += (red[0][dd] * (1.f / N_)) * W_out[dd * O_ + t];
        out[b * O_ + t] = acc;
    }
}

extern "C" void kernel_launch(void* const* d_in, const int* in_sizes, int n_in,
                              void* d_out, int out_size, void* d_ws, size_t ws_size,
                              hipStream_t stream) {
    const float* nodes = (const float*)d_in[0];
    const float* edges = (const float*)d_in[1];
    const float* W_emb = (const float*)d_in[2];
    const float* b_emb = (const float*)d_in[3];
    const float* Wf0   = (const float*)d_in[4];
    const float* w1_0  = (const float*)d_in[5];
    const float* b1_0  = (const float*)d_in[6];
    const float* w2_0  = (const float*)d_in[7];
    const float* b2_0  = (const float*)d_in[8];
    const float* bias0 = (const float*)d_in[9];
    const float* Wf1   = (const float*)d_in[10];
    const float* w1_1  = (const float*)d_in[11];
    const float* b1_1  = (const float*)d_in[12];
    const float* w2_1  = (const float*)d_in[13];
    const float* b2_1  = (const float*)d_in[14];
    const float* bias1 = (const float*)d_in[15];
    const float* W_out = (const float*)d_in[16];
    const float* b_out = (const float*)d_in[17];

    float* ws     = (float*)d_ws;               // ~25.7 MB total
    float* state0 = ws;                          // B*N*H      = 524288
    float* state1 = state0 + 524288;             // B*N*D1     = 2097152
    float* state2 = state1 + 2097152;            // B*N*H      = 524288
    float* Wh     = state2 + 524288;             // EH*B*N*H   = 2097152
    float* a1     = Wh + 2097152;                // EH*B*N     = 32768
    float* a2     = a1 + 32768;
    float* pm     = a2 + 32768;                  // NC*EH*B*N  = 524288
    float* psum   = pm + 524288;
    float* mcol   = psum + 524288;               // EH*B*N
    float* invS   = mcol + 32768;

    embed_kernel<<<BN_ / 4, 256, 0, stream>>>(nodes, W_emb, b_emb, state0);

    // ---- layer 0
    wh_a_kernel<H_><<<EH_ * BN_, 64, 0, stream>>>(state0, Wf0, w1_0, b1_0, w2_0, b2_0,
                                                  Wh, a1, a2);
    stats_kernel<<<B_ * NC_ * (N_ / 256), 256, 0, stream>>>(edges, a1, a2, pm, psum);
    combine_kernel<<<EH_ * BN_ / 256, 256, 0, stream>>>(pm, psum, mcol, invS);
    mac_kernel<0><<<B_ * (N_ / TI_), 512, 0, stream>>>(edges, a1, a2, mcol, invS, Wh,
                                                       bias0, state1);
    // ---- layer 1
    wh_a_kernel<D1_><<<EH_ * BN_, 64, 0, stream>>>(state1, Wf1, w1_1, b1_1, w2_1, b2_1,
                                                   Wh, a1, a2);
    stats_kernel<<<B_ * NC_ * (N_ / 256), 256, 0, stream>>>(edges, a1, a2, pm, psum);
    combine_kernel<<<EH_ * BN_ / 256, 256, 0, stream>>>(pm, psum, mcol, invS);
    mac_kernel<1><<<B_ * (N_ / TI_), 512, 0, stream>>>(edges, a1, a2, mcol, invS, Wh,
                                                       bias1, state2);

    out_kernel<<<B_, 256, 0, stream>>>(state2, W_out, b_out, (float*)d_out);
}